// Round 11
// baseline (175.261 us; speedup 1.0000x reference)
//
#include <hip/hip_runtime.h>
#include <hip/hip_bf16.h>

// Fused QKV projection + 16-head self-attention. S=2048, B=2, H=1024, NH=16, DH=64.
// Inputs fp32, output fp32. bf16 internal compute (2% rel threshold).
//
// R23: attn waves process 64 q-rows each (two Q B-fragments share every K/V
// A-fragment read) -> LDS bytes per unit work HALVED (16 ds_reads : 32 MFMAs
// vs 16:16). R22's counters put LDS-pipe at ~54% of the tile window (tallest
// pole); R16/R19 proved waves/SIMD isn't binding, so trading occupancy
// (2 waves/SIMD -> 1) for 2x per-wave intensity + 2x within-wave ILP attacks
// the measured consumer. Block = 2 waves x 64 q = 128 q; grid (16,32) = 512
// blocks = 2 blocks/CU (cross-block stage/compute overlap preserved).
// All fragment/swizzle math unchanged; qh is a register-index replication.
// Everything else byte-identical to R22 (5-round-proven pieces).
//
// d_ws: qb[hb][s][d] 8MB | kb[hb][s][d] 8MB | vtb[hb][d][s] 8MB  (hb = h*2+b)

typedef __hip_bfloat16 bf16;
typedef __bf16 bfr;
typedef __attribute__((ext_vector_type(8))) __bf16 bf16x8;
typedef __attribute__((ext_vector_type(4))) __bf16 bf16x4;
typedef __attribute__((ext_vector_type(2))) __bf16 bf16x2;
typedef __attribute__((ext_vector_type(4))) float f32x4;
typedef __attribute__((ext_vector_type(16))) float f32x16;
typedef __attribute__((ext_vector_type(4))) unsigned u32x4;

#define S_SEQ  2048
#define HID    1024
#define OUT3   3072
#define NROWS  4096

#if __has_builtin(__builtin_amdgcn_exp2f)
#define EXP2F(x) __builtin_amdgcn_exp2f(x)
#else
#define EXP2F(x) exp2f(x)
#endif

// q pre-scale: (1/sqrt(64)) * log2(e) -> scores in base-2 domain
#define QSCALE 0.18033688011112042f

// ---------------------------------------------------------------------------
// Fused cast: fp32 -> bf16 for X then W (verified R9/R10).
// ---------------------------------------------------------------------------
__global__ __launch_bounds__(256) void cast_both_kernel(
    const float* __restrict__ X, bfr* __restrict__ Xb,
    const float* __restrict__ W, bfr* __restrict__ Wb)
{
    int bid = blockIdx.x;
    const float* src;
    bfr* dst;
    int lid;
    if (bid < NROWS * HID / 2048) { src = X; dst = Xb; lid = bid; }
    else { src = W; dst = Wb; lid = bid - NROWS * HID / 2048; }
    int gid = lid * 256 + threadIdx.x;
    const float4* s4 = (const float4*)src;
    float4 a = s4[(size_t)gid * 2];
    float4 b = s4[(size_t)gid * 2 + 1];
    bf16x8 v;
    v[0] = (bfr)a.x; v[1] = (bfr)a.y; v[2] = (bfr)a.z; v[3] = (bfr)a.w;
    v[4] = (bfr)b.x; v[5] = (bfr)b.y; v[6] = (bfr)b.z; v[7] = (bfr)b.w;
    *(bf16x8*)(dst + (size_t)gid * 8) = v;
}

// ---------------------------------------------------------------------------
// MFMA GEMM (m97 recipe). Epilogue: qb (pre-scaled), kb stored directly
// (32B-contiguous per 16 lanes); vtb (V^T, the 4KB-stride case) goes through
// an LDS transpose reusing the As/Bs region, then coalesced bf16x8 stores.
// ---------------------------------------------------------------------------
__device__ __forceinline__ void gload_lds16(const void* g, void* l) {
    __builtin_amdgcn_global_load_lds(
        (const __attribute__((address_space(1))) unsigned int*)g,
        (__attribute__((address_space(3))) unsigned int*)l, 16, 0, 0);
}

__global__ __launch_bounds__(256, 3) void qkv_gemm_mfma(
    const bfr* __restrict__ Xb, const bfr* __restrict__ Wb,
    const float* __restrict__ bias,
    bfr* __restrict__ qb, bfr* __restrict__ kb, bfr* __restrict__ vtb)
{
    __shared__ __attribute__((aligned(16))) unsigned char lds_all[32768];
    bfr* As = (bfr*)lds_all;              // 128x64 bf16 = 16384 B
    bfr* Bs = (bfr*)(lds_all + 16384);    // 128x64 bf16 = 16384 B
    bfr* Tr = (bfr*)lds_all;              // epilogue V^T buf: 64 x 144 = 18432 B

    const int o0 = blockIdx.x * 128;
    const int r0 = blockIdx.y * 128;
    const int tid = threadIdx.x;
    const int lane = tid & 63;
    const int w = tid >> 6;
    const int l15 = lane & 15;
    const int quad = lane >> 4;
    const int m0 = (w & 1) * 64;
    const int n0 = (w >> 1) * 64;

    f32x4 acc[4][4];
#pragma unroll
    for (int mi = 0; mi < 4; mi++)
#pragma unroll
        for (int ni = 0; ni < 4; ni++) acc[mi][ni] = {0.f, 0.f, 0.f, 0.f};

    for (int k0 = 0; k0 < HID; k0 += 64) {
#pragma unroll
        for (int i = 0; i < 4; i++) {
            int c = i * 256 + tid;
            int row = c >> 3, c8 = c & 7;
            gload_lds16(Xb + (size_t)(r0 + row) * HID + k0 + c8 * 8, As + c * 8);
            gload_lds16(Wb + (size_t)(o0 + row) * HID + k0 + c8 * 8, Bs + c * 8);
        }
        __syncthreads();

#pragma unroll
        for (int ks = 0; ks < 2; ks++) {
            bf16x8 af[4], bfg[4];
#pragma unroll
            for (int mi = 0; mi < 4; mi++)
                af[mi] = *(const bf16x8*)(As + (m0 + mi * 16 + l15) * 64 + ks * 32 + quad * 8);
#pragma unroll
            for (int ni = 0; ni < 4; ni++)
                bfg[ni] = *(const bf16x8*)(Bs + (n0 + ni * 16 + l15) * 64 + ks * 32 + quad * 8);
#pragma unroll
            for (int mi = 0; mi < 4; mi++)
#pragma unroll
                for (int ni = 0; ni < 4; ni++)
                    acc[mi][ni] = __builtin_amdgcn_mfma_f32_16x16x32_bf16(
                        af[mi], bfg[ni], acc[mi][ni], 0, 0, 0);
        }
        __syncthreads();   // also makes As/Bs safe to reuse as Tr after loop
    }

    // --- epilogue. C/D layout: col=l15, row=quad*4+r.
    const int omod = o0 % 192;
#pragma unroll
    for (int ni = 0; ni < 4; ni++) {
        int cb = o0 + n0 + ni * 16;
        int h = cb / 192;
        int rem = cb % 192;
        int t = rem >> 6;
        int d = (rem & 63) + l15;
        float bv = bias[cb + l15];
        if (t == 2) {
#pragma unroll
            for (int mi = 0; mi < 4; mi++)
#pragma unroll
                for (int r = 0; r < 4; r++) {
                    int grl = m0 + mi * 16 + quad * 4 + r;   // 0..127
                    Tr[(size_t)d * 144 + (grl & 1) * 72 + (grl >> 1)]
                        = (bfr)(acc[mi][ni][r] + bv);
                }
        } else {
#pragma unroll
            for (int mi = 0; mi < 4; mi++)
#pragma unroll
                for (int r = 0; r < 4; r++) {
                    int gr = r0 + m0 + mi * 16 + quad * 4 + r;
                    int s = gr >> 1, b = gr & 1;
                    int hb = h * 2 + b;
                    float val = acc[mi][ni][r] + bv;
                    if (t == 0)
                        qb[((size_t)hb * S_SEQ + s) * 64 + d] = (bfr)(val * QSCALE);
                    else
                        kb[((size_t)hb * S_SEQ + s) * 64 + d] = (bfr)val;
                }
        }
    }
    if (omod != 0) {          // block-uniform: this block produced a V tile
        __syncthreads();      // Tr writes visible
        int ht = (omod == 64) ? (o0 + 64) / 192 : o0 / 192;
        int d = tid >> 2;
        int b = (tid >> 1) & 1;
        int chunk = tid & 1;            // 32-s half
        int s0 = r0 >> 1;
        int hb = ht * 2 + b;
        const bfr* src = Tr + (size_t)d * 144 + b * 72 + chunk * 32;
        bfr* dstp = vtb + ((size_t)hb * 64 + d) * S_SEQ + s0 + chunk * 32;
#pragma unroll
        for (int j = 0; j < 4; j++)
            *(bf16x8*)(dstp + j * 8) = *(const bf16x8*)(src + j * 8);
    }
}

// ---------------------------------------------------------------------------
// Attention, 32x32x16 MFMA, 64 q-rows per wave, single-pass (32 key-tiles).
// Block = 2 waves x 64 q = 128 q rows, one hb. Grid (16, 32) = 512 blocks,
// 128 threads. Per tile, per wave: 8 kf reads feed 16 QK MFMAs (2 q-halves
// share each kf); 8 vf reads feed 16 PV MFMAs. Layouts unchanged from R22:
//   S^T = K*Q^T : A=K rows (lane&31=key), B=Q^T regs (lane&31=q within qh).
//   C/D: col=lane&31=q, row(key)=(r&3)+8*(r>>2)+4*(lane>>5).
//   softmax in-register per qh: EXP2F + bf16 pair-pack + permlane32_swap.
// LDS: 2-deep ring of {K[64][64], V^T[64][64]} bf16 = 32 KB; linear 128B rows;
// XOR swizzle slot = chunk16B ^ (row&7) on the global source AND the ds_read
// address (rule 21). Schedule per tile t: vmcnt(0); barrier; STAGE(t+1);
// compute(t). (Ring + schedule HW-validated R19/R22.)
// ---------------------------------------------------------------------------
__device__ __forceinline__ void plswap(unsigned &a, unsigned &b) {
    asm volatile("v_permlane32_swap_b32 %0, %1" : "+v"(a), "+v"(b));
}

__global__ __launch_bounds__(128, 2) void attn32_kernel(
    const bfr* __restrict__ qb, const bfr* __restrict__ kb,
    const bfr* __restrict__ vtb, float* __restrict__ out)
{
    // [buf][K=0/V=1][row*64 + elem]; 2 * 2 * 8KB = 32KB
    __shared__ __attribute__((aligned(16))) bfr KV[2][2][64 * 64];

    constexpr int NT = 32;               // 64-key tiles per block
    const int qt = blockIdx.x;
    const int hb = blockIdx.y;
    const int h = hb >> 1, b = hb & 1;
    const int tid = threadIdx.x;         // 0..127
    const int lane = tid & 63;
    const int w = tid >> 6;              // wave 0/1
    const int l31 = lane & 31;
    const int hi = lane >> 5;
    const size_t hboff = (size_t)hb * S_SEQ * 64;

    const int srow = tid >> 3;           // staging row (0..15), +16*i
    const int slot = tid & 7;            // 16B slot within the 128B row

    const int qbase = qt * 128 + w * 64; // wave's 64-q strip
    bf16x8 qf[2][4];                     // [qh][kk]: k=d in [kk*16+hi*8, +8)
#pragma unroll
    for (int qh = 0; qh < 2; qh++)
#pragma unroll
        for (int kk = 0; kk < 4; kk++)
            qf[qh][kk] = *(const bf16x8*)(qb + hboff
                + (size_t)(qbase + qh * 32 + l31) * 64 + kk * 16 + hi * 8);

    f32x16 Oacc[2][2];                   // [dt][qh]
#pragma unroll
    for (int dt = 0; dt < 2; dt++)
#pragma unroll
        for (int qh = 0; qh < 2; qh++)
#pragma unroll
            for (int i = 0; i < 16; i++) Oacc[dt][qh][i] = 0.f;
    float lsum0 = 0.f, lsum1 = 0.f;      // per-lane partials (own keys only)

    // Stage tile t into buf t&1. 128 threads x 8 gload_lds (4 K + 4 V).
    // LDS dest linear (i*2KB + tid*16B == row*128 + slot*16); global chunk
    // gc = slot ^ (row&7)  (inverse-swizzled source).
#define STAGE(t_) do {                                                         \
    int kt__ = (t_); int bf__ = kt__ & 1;                                      \
    _Pragma("unroll")                                                          \
    for (int i = 0; i < 4; i++) {                                              \
        int r = i * 16 + srow;                                                 \
        int gc = slot ^ (r & 7);                                               \
        gload_lds16(kb + hboff + (size_t)(kt__ * 64 + r) * 64 + gc * 8,        \
                    (bfr*)&KV[bf__][0][0] + i * 1024 + tid * 8);               \
    }                                                                          \
    _Pragma("unroll")                                                          \
    for (int i = 0; i < 4; i++) {                                              \
        int r = i * 16 + srow;                                                 \
        int gc = slot ^ (r & 7);                                               \
        gload_lds16(vtb + hboff + (size_t)r * S_SEQ + kt__ * 64 + gc * 8,      \
                    (bfr*)&KV[bf__][1][0] + i * 1024 + tid * 8);               \
    }                                                                          \
} while (0)

    STAGE(0);

    for (int t = 0; t < NT; t++) {
        // Loads for tile t issued one compute phase ago (prologue for t=0).
        asm volatile("s_waitcnt vmcnt(0)" ::: "memory");
        __builtin_amdgcn_s_barrier();    // + proves buf (t+1)&1 reads done
        if (t + 1 < NT) STAGE(t + 1);

        const bfr* Kb = &KV[t & 1][0][0];
        const bfr* Vb = &KV[t & 1][1][0];

        // --- S^T = K Q^T (base-2 domain): each kf feeds both q-halves ---
        unsigned wds0[2][8], wds1[2][8]; // [ts][a] packed bf16 pairs, per qh
        float rs0 = 0.f, rs1 = 0.f;
#pragma unroll
        for (int ts = 0; ts < 2; ts++) {
            const int krow = ts * 32 + l31;
            f32x16 sc0, sc1;
#pragma unroll
            for (int i = 0; i < 16; i++) { sc0[i] = 0.f; sc1[i] = 0.f; }
#pragma unroll
            for (int kk = 0; kk < 4; kk++) {
                int ks = (kk * 2 + hi) ^ (krow & 7);
                bf16x8 kf = *(const bf16x8*)(Kb + krow * 64 + ks * 8);
                sc0 = __builtin_amdgcn_mfma_f32_32x32x16_bf16(kf, qf[0][kk], sc0, 0, 0, 0);
                sc1 = __builtin_amdgcn_mfma_f32_32x32x16_bf16(kf, qf[1][kk], sc1, 0, 0, 0);
            }
            // keys(r) = (r&3) + 8*(r>>2) + 4*hi; pairs r=2a,2a+1 contiguous
#pragma unroll
            for (int a = 0; a < 8; a++) {
                float p0 = EXP2F(sc0[2 * a]);
                float p1 = EXP2F(sc0[2 * a + 1]);
                rs0 += p0 + p1;
                bf16x2 pk0; pk0[0] = (bfr)p0; pk0[1] = (bfr)p1;
                wds0[ts][a] = __builtin_bit_cast(unsigned, pk0);
                float p2 = EXP2F(sc1[2 * a]);
                float p3 = EXP2F(sc1[2 * a + 1]);
                rs1 += p2 + p3;
                bf16x2 pk1; pk1[0] = (bfr)p2; pk1[1] = (bfr)p3;
                wds1[ts][a] = __builtin_bit_cast(unsigned, pk1);
            }
        }
        lsum0 += rs0;
        lsum1 += rs1;

        // --- redistribute into PV B-frags per qh: swap(w[a], w[a+2]) ---
        bf16x8 pfrag0[4], pfrag1[4];
#pragma unroll
        for (int c = 0; c < 4; c++) {
            int ts = c >> 1, cc = c & 1;
            {
                unsigned w0 = wds0[ts][cc * 4 + 0];
                unsigned w1 = wds0[ts][cc * 4 + 1];
                unsigned w2 = wds0[ts][cc * 4 + 2];
                unsigned w3 = wds0[ts][cc * 4 + 3];
                plswap(w0, w2);
                plswap(w1, w3);
                u32x4 pw; pw[0] = w0; pw[1] = w1; pw[2] = w2; pw[3] = w3;
                pfrag0[c] = __builtin_bit_cast(bf16x8, pw);
            }
            {
                unsigned w0 = wds1[ts][cc * 4 + 0];
                unsigned w1 = wds1[ts][cc * 4 + 1];
                unsigned w2 = wds1[ts][cc * 4 + 2];
                unsigned w3 = wds1[ts][cc * 4 + 3];
                plswap(w0, w2);
                plswap(w1, w3);
                u32x4 pw; pw[0] = w0; pw[1] = w1; pw[2] = w2; pw[3] = w3;
                pfrag1[c] = __builtin_bit_cast(bf16x8, pw);
            }
        }

        // --- O^T += V^T P^T : each vf feeds both q-halves ---
#pragma unroll
        for (int kk = 0; kk < 4; kk++)
#pragma unroll
            for (int dt = 0; dt < 2; dt++) {
                int vrow = dt * 32 + l31;
                int vs = (kk * 2 + hi) ^ (vrow & 7);
                bf16x8 vf = *(const bf16x8*)(Vb + vrow * 64 + vs * 8);
                Oacc[dt][0] = __builtin_amdgcn_mfma_f32_32x32x16_bf16(vf, pfrag0[kk], Oacc[dt][0], 0, 0, 0);
                Oacc[dt][1] = __builtin_amdgcn_mfma_f32_32x32x16_bf16(vf, pfrag1[kk], Oacc[dt][1], 0, 0, 0);
            }
    }
#undef STAGE

    // --- epilogue: O^T[d][q] -> out[s][b][h*64+d], float4 stores, per qh ---
    lsum0 += __shfl_xor(lsum0, 32);
    lsum1 += __shfl_xor(lsum1, 32);
#pragma unroll
    for (int qh = 0; qh < 2; qh++) {
        float inv = 1.0f / (qh == 0 ? lsum0 : lsum1);
        int qrow = qbase + qh * 32 + l31;
        float* orow = out + ((size_t)qrow * 2 + b) * HID + h * 64;
#pragma unroll
        for (int dt = 0; dt < 2; dt++)
#pragma unroll
            for (int g = 0; g < 4; g++) {
                float4 o4;
                o4.x = Oacc[dt][qh][4 * g + 0] * inv;
                o4.y = Oacc[dt][qh][4 * g + 1] * inv;
                o4.z = Oacc[dt][qh][4 * g + 2] * inv;
                o4.w = Oacc[dt][qh][4 * g + 3] * inv;
                *(float4*)(orow + dt * 32 + 8 * g + 4 * hi) = o4;
            }
    }
}

// ---------------------------------------------------------------------------
extern "C" void kernel_launch(void* const* d_in, const int* in_sizes, int n_in,
                              void* d_out, int out_size, void* d_ws, size_t ws_size,
                              hipStream_t stream) {
    const float* X    = (const float*)d_in[0];
    const float* W    = (const float*)d_in[1];
    const float* bias = (const float*)d_in[2];
    float* out = (float*)d_out;

    bfr* qb  = (bfr*)d_ws;
    bfr* kb  = qb + (size_t)32 * S_SEQ * 64;
    bfr* vtb = kb + (size_t)32 * S_SEQ * 64;

    // d_out as cast scratch (14.7 MB <= 16.8 MB); attention overwrites it last.
    bfr* Xb = (bfr*)d_out;
    bfr* Wb = Xb + (size_t)NROWS * HID;

    cast_both_kernel<<<(NROWS * HID + OUT3 * HID) / 2048, 256, 0, stream>>>(X, Xb, W, Wb);

    dim3 g1(OUT3 / 128, NROWS / 128);           // 24 x 32 = 768 blocks
    qkv_gemm_mfma<<<g1, 256, 0, stream>>>(Xb, Wb, bias, qb, kb, vtb);

    dim3 g2(S_SEQ / 128, 32);                   // 16 x 32 = 512 blocks, 128 thr
    attn32_kernel<<<g2, 128, 0, stream>>>(qb, kb, vtb, out);
}